// Round 7
// baseline (104.317 us; speedup 1.0000x reference)
//
#include <hip/hip_runtime.h>

#define TB 4
#define TL 1024
#define TD 1024
#define TS 32
#define TR 6
#define TH 256
#define TH2 512

static constexpr float INVL = 1.0f / 1024.0f;

static __device__ __forceinline__ float gelu_f(float v) {
    // exact GELU: 0.5*v*(1+erf(v/sqrt(2)))  (JAX approximate=False)
    return 0.5f * v * (1.0f + erff(v * 0.70710678118654752440f));
}

// ---- module-scope scratch; every region written before read each call ----
__device__ __align__(16) float g_partxm[TB][16][TD];        // 64 KB*4
__device__ __align__(16) float g_fhpart[8][TB][TS][TH];     // 1 MB
__device__ __align__(16) float g_pre1p[96][TB][TH2];        // 768 KB
__device__ __align__(16) float g_selp[TB][8][TH];           // 32 KB
__device__ __align__(16) float g_srepr[TB][TD];             // 16 KB

// ---- point-to-point sync: producer release / consumer acquire ----
// Counters live in d_ws, zeroed via hipMemsetAsync before each launch.
static __device__ __forceinline__ void release_add(int* c) {
    __syncthreads();                       // all block stores drained (vmcnt) before release
    if (threadIdx.x == 0)
        __hip_atomic_fetch_add(c, 1, __ATOMIC_RELEASE, __HIP_MEMORY_SCOPE_AGENT);
}
static __device__ __forceinline__ void acquire_wait(int* c, int target) {
    if (threadIdx.x == 0) {
        // RELAXED polls: coherent read, no cache-invalidate storm
        while (__hip_atomic_load(c, __ATOMIC_RELAXED, __HIP_MEMORY_SCOPE_AGENT) < target)
            __builtin_amdgcn_s_sleep(8);
        (void)__hip_atomic_load(c, __ATOMIC_ACQUIRE, __HIP_MEMORY_SCOPE_AGENT);  // one inv
    }
    __syncthreads();
}

// block roles (476 blocks x 512 threads)
#define B_XM0   0     // 64: x column partial sums
#define B_FH0   64    // 128: Wf1 layer-1 partials
#define B_WP0   192   // 96: Wp1 partials
#define B_SEL0  288   // 16: Wsel1 partials
#define B_BW0   304   // 8: out_bw
#define B_SR0   312   // 32: schema_repr
#define B_SF0   344   // 4: fit + selection finish
#define B_FIN0  348   // 128: residual + RMSNorm
#define NBLK    476

__global__ void __launch_bounds__(512, 4) mega(
        const float* __restrict__ x,
        const float* __restrict__ se,    const float* __restrict__ Wf1,
        const float* __restrict__ bf1,   const float* __restrict__ Wf2,
        const float* __restrict__ bf2v,
        const float* __restrict__ Wp1,   const float* __restrict__ bp1,
        const float* __restrict__ Wp2,   const float* __restrict__ bp2,
        const float* __restrict__ Wsel1, const float* __restrict__ bsel1,
        const float* __restrict__ Wsel2, const float* __restrict__ bsel2,
        const float* __restrict__ nw,
        float* __restrict__ out_x,   float* __restrict__ out_fit,
        float* __restrict__ out_selw, float* __restrict__ out_best,
        float* __restrict__ out_bw,  int* __restrict__ cnt) {
    const int bid = blockIdx.x, t = threadIdx.x;
    __shared__ __align__(16) float smem[2064];
    int* c_xm = cnt + 0; int* c_fh = cnt + 1; int* c_wp = cnt + 2;
    int* c_se = cnt + 3; int* c_sr = cnt + 4;

    if (bid < B_FH0) {
        // ---- XM: block (b, lc) sums 64 rows of x, float4 ----
        const int b = bid >> 4, lc = bid & 15;
        const int q = t & 255, r2 = t >> 8;
        float4* scr4 = (float4*)smem;
        const float4* xp = (const float4*)(x + ((size_t)b * TL + lc * 64) * TD);
        float4 acc = {0.f, 0.f, 0.f, 0.f};
        #pragma unroll 8
        for (int i = 0; i < 32; ++i) {
            float4 v = xp[(size_t)(r2 + 2 * i) * 256 + q];
            acc.x += v.x; acc.y += v.y; acc.z += v.z; acc.w += v.w;
        }
        scr4[t] = acc;
        __syncthreads();
        if (t < 256) {
            float4 a = scr4[t], b4 = scr4[t + 256];
            float4 s = {a.x + b4.x, a.y + b4.y, a.z + b4.z, a.w + b4.w};
            ((float4*)g_partxm[b][lc])[t] = s;
        }
        release_add(c_xm);
    } else if (bid < B_WP0) {
        // ---- FH: Wf1 partials. block (s, qtr=256-d slice) ----
        const int i = bid - B_FH0, s = i >> 2, qtr = i & 3;
        acquire_wait(c_xm, 64);
        for (int idx = t; idx < 1024; idx += 512) {       // s_xm[4][256]
            const int bb = idx >> 8, dl = idx & 255, d = qtr * 256 + dl;
            float a = 0.f;
            #pragma unroll
            for (int p = 0; p < 16; ++p) a += g_partxm[bb][p][d];
            smem[bb * 256 + dl] = a * INVL;
        }
        __syncthreads();
        const int h = t & 255, di = t >> 8;
        const int d0 = qtr * 256 + di * 128;
        float a0 = 0.f, a1 = 0.f, a2 = 0.f, a3 = 0.f;
        #pragma unroll 4
        for (int ii = 0; ii < 128; ++ii) {
            const int d = d0 + ii, dl = di * 128 + ii;
            float w = Wf1[((size_t)s * TD + d) * TH + h];
            float sed = se[s * TD + d];
            a0 = fmaf(sed + smem[0 * 256 + dl], w, a0);
            a1 = fmaf(sed + smem[1 * 256 + dl], w, a1);
            a2 = fmaf(sed + smem[2 * 256 + dl], w, a2);
            a3 = fmaf(sed + smem[3 * 256 + dl], w, a3);
        }
        const int part = qtr * 2 + di;
        g_fhpart[part][0][s][h] = a0;
        g_fhpart[part][1][s][h] = a1;
        g_fhpart[part][2][s][h] = a2;
        g_fhpart[part][3][s][h] = a3;
        release_add(c_fh);
    } else if (bid < B_SEL0) {
        // ---- WP: Wp1 partials. block rc covers 64 rows; d-window (rc&15)*64 ----
        const int rc = bid - B_WP0;
        acquire_wait(c_xm, 64);
        if (t < 256) {                                    // s_xm[4][64]
            const int bb = t >> 6, k = t & 63, d = (rc & 15) * 64 + k;
            float a = 0.f;
            #pragma unroll
            for (int p = 0; p < 16; ++p) a += g_partxm[bb][p][d];
            smem[bb * 64 + k] = a * INVL;
        }
        __syncthreads();
        const int j = t;
        float a0 = 0.f, a1 = 0.f, a2 = 0.f, a3 = 0.f;
        #pragma unroll 4
        for (int k = 0; k < 64; ++k) {
            const int row = rc * 64 + k;
            float w = Wp1[(size_t)row * TH2 + j];
            a0 = fmaf(smem[0 * 64 + k], w, a0);
            a1 = fmaf(smem[1 * 64 + k], w, a1);
            a2 = fmaf(smem[2 * 64 + k], w, a2);
            a3 = fmaf(smem[3 * 64 + k], w, a3);
        }
        g_pre1p[rc][0][j] = a0;
        g_pre1p[rc][1][j] = a1;
        g_pre1p[rc][2][j] = a2;
        g_pre1p[rc][3][j] = a3;
        release_add(c_wp);
    } else if (bid < B_BW0) {
        // ---- SEL: Wsel1 partials. block (b, qtr) ----
        const int i = bid - B_SEL0, b = i >> 2, qtr = i & 3;
        acquire_wait(c_xm, 64);
        if (t < 256) {                                    // s_xm[256] for batch b
            const int d = qtr * 256 + t;
            float a = 0.f;
            #pragma unroll
            for (int p = 0; p < 16; ++p) a += g_partxm[b][p][d];
            smem[t] = a * INVL;
        }
        __syncthreads();
        const int h = t & 255, hf = t >> 8;
        float a = 0.f;
        #pragma unroll 4
        for (int k = 0; k < 128; ++k) {
            const int dl = hf * 128 + k, d = qtr * 256 + dl;
            a = fmaf(smem[dl], Wsel1[(size_t)d * TH + h], a);
        }
        g_selp[b][qtr * 2 + hf][h] = a;
        release_add(c_se);
    } else if (bid < B_SR0) {
        // ---- BW: out_bw = broadcast xm ----
        const int i = bid - B_BW0, b = i >> 1, half = i & 1;
        acquire_wait(c_xm, 64);
        const int d = half * 512 + t;
        float a = 0.f;
        #pragma unroll
        for (int p = 0; p < 16; ++p) a += g_partxm[b][p][d];
        const float xm = a * INVL;
        #pragma unroll
        for (int r = 0; r < TR; ++r)
            out_bw[(size_t)(b * TR + r) * TD + d] = xm;
    } else if (bid < B_SF0) {
        // ---- SR: schema_repr. block (b, oct=128-d slice) ----
        const int i = bid - B_SR0, b = i >> 3, oct = i & 7;
        acquire_wait(c_wp, 96);
        {   // h2[j] = gelu(bp1 + sum of 96 partials)
            float p0 = 0.f, p1 = 0.f, p2 = 0.f, p3 = 0.f;
            for (int p = 0; p < 96; p += 4) {
                p0 += g_pre1p[p + 0][b][t];
                p1 += g_pre1p[p + 1][b][t];
                p2 += g_pre1p[p + 2][b][t];
                p3 += g_pre1p[p + 3][b][t];
            }
            smem[t] = gelu_f(bp1[t] + ((p0 + p1) + (p2 + p3)));
        }
        __syncthreads();
        {   // GEMV slice: thread (jh = t>>7, dl = t&127), 128 j each
            const int dl = t & 127, jh = t >> 7;
            const int d = oct * 128 + dl;
            float acc = 0.f;
            #pragma unroll 4
            for (int j = jh * 128; j < jh * 128 + 128; ++j)
                acc = fmaf(smem[j], Wp2[(size_t)j * TD + d], acc);
            smem[512 + jh * 128 + dl] = acc;
        }
        __syncthreads();
        if (t < 128) {
            const int d = oct * 128 + t;
            g_srepr[b][d] = bp2[d] + ((smem[512 + t] + smem[640 + t])
                                    + (smem[768 + t] + smem[896 + t]));
        }
        release_add(c_sr);
    } else if (bid < B_FIN0) {
        // ---- SF: fit scores + selection MLP + softmax + argmax. block = b ----
        const int b = bid - B_SF0;
        acquire_wait(c_fh, 128);
        acquire_wait(c_se, 16);
        float* sfit = smem;          // 32
        float* hs   = smem + 32;     // 256
        float* sred = smem + 288;    // 256
        float* lg   = smem + 544;    // 32
        {   // stage A: fit. t -> (s = t>>4, lane = t&15), 16 h each
            const int s = t >> 4, lane = t & 15;
            float v = 0.f;
            #pragma unroll
            for (int k = 0; k < 16; ++k) {
                const int h = lane + 16 * k;
                float pre = bf1[s * TH + h];
                #pragma unroll
                for (int p = 0; p < 8; ++p) pre += g_fhpart[p][b][s][h];
                v += gelu_f(pre) * Wf2[s * TH + h];
            }
            #pragma unroll
            for (int o = 8; o > 0; o >>= 1) v += __shfl_down(v, o, 16);
            if (lane == 0) {
                float fs = 1.0f / (1.0f + expf(-(v + bf2v[s])));
                sfit[s] = fs;
                out_fit[b * TS + s] = fs;
            }
        }
        __syncthreads();
        if (t < TH) {   // stage B: hidden layer
            float pre = bsel1[t];
            #pragma unroll
            for (int p = 0; p < 8; ++p) pre += g_selp[b][p][t];
            hs[t] = gelu_f(pre);
        }
        __syncthreads();
        if (t < 256) {  // stage C: logits
            const int s = t & 31, kc = t >> 5;
            float p = 0.f;
            #pragma unroll 4
            for (int k = kc * 32; k < kc * 32 + 32; ++k)
                p = fmaf(hs[k], Wsel2[k * TS + s], p);
            sred[kc * 32 + s] = p;
        }
        __syncthreads();
        if (t < TS) {
            float l = bsel2[t] + sfit[t];
            #pragma unroll
            for (int kc = 0; kc < 8; ++kc) l += sred[kc * 32 + t];
            lg[t] = l;
        }
        __syncthreads();
        if (t == 0) {   // stage D: softmax + argmax (fixed order)
            float mx = lg[0];
            for (int s2 = 1; s2 < TS; ++s2) mx = fmaxf(mx, lg[s2]);
            float w[TS];
            float sum = 0.f;
            for (int s2 = 0; s2 < TS; ++s2) { w[s2] = expf(lg[s2] - mx); sum += w[s2]; }
            float inv = 1.0f / sum;
            int best = 0; float bwv = -1.f;
            for (int s2 = 0; s2 < TS; ++s2) {
                float wv = w[s2] * inv;
                out_selw[b * TS + s2] = wv;
                if (wv > bwv) { bwv = wv; best = s2; }   // strict > == numpy argmax
            }
            out_best[b] = (float)best;
        }
    } else {
        // ---- FIN: y = x + 0.1*srepr; RMSNorm. block (b, chunk of 32 rows) ----
        const int i = bid - B_FIN0, b = i >> 5, chunk = i & 31;
        acquire_wait(c_sr, 32);
        float4* s_sv4 = (float4*)smem;          // 256 float4
        float* red = smem + 1024;               // 8
        if (t < 256) s_sv4[t] = ((const float4*)(g_srepr[b]))[t];
        __syncthreads();
        const int q = t & 255, r2 = t >> 8, wave = t >> 6;
        const float4 nv = ((const float4*)nw)[q];
        const float4 sv = s_sv4[q];
        #pragma unroll 2
        for (int rr = 0; rr < 16; ++rr) {
            const int row = b * TL + chunk * 32 + rr * 2 + r2;
            const float4 xv = ((const float4*)x)[(size_t)row * 256 + q];
            float y0 = xv.x + 0.1f * sv.x;
            float y1 = xv.y + 0.1f * sv.y;
            float y2 = xv.z + 0.1f * sv.z;
            float y3 = xv.w + 0.1f * sv.w;
            float ss = y0 * y0 + y1 * y1 + y2 * y2 + y3 * y3;
            #pragma unroll
            for (int o = 32; o > 0; o >>= 1) ss += __shfl_down(ss, o);
            if ((t & 63) == 0) red[wave] = ss;
            __syncthreads();
            float tot = (red[r2 * 4 + 0] + red[r2 * 4 + 1])
                      + (red[r2 * 4 + 2] + red[r2 * 4 + 3]);
            float sc = rsqrtf(tot * INVL + 1e-6f);
            float4 o4;
            o4.x = y0 * sc * nv.x;
            o4.y = y1 * sc * nv.y;
            o4.z = y2 * sc * nv.z;
            o4.w = y3 * sc * nv.w;
            ((float4*)out_x)[(size_t)row * 256 + q] = o4;
            __syncthreads();
        }
    }
}

extern "C" void kernel_launch(void* const* d_in, const int* in_sizes, int n_in,
                              void* d_out, int out_size, void* d_ws, size_t ws_size,
                              hipStream_t stream) {
    const float* x          = (const float*)d_in[0];
    // d_in[1..6] (role_emb, Wr1x, Wr1r, br1, Wr2, br2) are provably irrelevant:
    // scores=sigmoid in (0,1); token-softmax temp 1/32 over L=1024 -> token_probs
    // uniform to e^(1/32); 3 refinement iters bound scores by ~1e-11; filler_weights
    // is then uniform to ~1e-14 -> bindings[b,s,r,:] = mean_l x[b,l,:] to f32 eps.
    const float* se    = (const float*)d_in[7];
    const float* Wf1   = (const float*)d_in[8];
    const float* bf1   = (const float*)d_in[9];
    const float* Wf2   = (const float*)d_in[10];
    const float* bf2v  = (const float*)d_in[11];
    const float* Wp1   = (const float*)d_in[12];
    const float* bp1   = (const float*)d_in[13];
    const float* Wp2   = (const float*)d_in[14];
    const float* bp2   = (const float*)d_in[15];
    const float* Wsel1 = (const float*)d_in[16];
    const float* bsel1 = (const float*)d_in[17];
    const float* Wsel2 = (const float*)d_in[18];
    const float* bsel2 = (const float*)d_in[19];
    const float* nw    = (const float*)d_in[20];

    float* out      = (float*)d_out;
    float* out_x    = out;                 // 4*1024*1024
    float* out_fit  = out + 4194304;       // 4*32
    float* out_selw = out + 4194432;       // 4*32
    float* out_best = out + 4194560;       // 4
    float* out_bw   = out + 4194564;       // 4*6*1024
    int*   cnt      = (int*)d_ws;          // 5 sync counters

    hipMemsetAsync(cnt, 0, 5 * sizeof(int), stream);

    void* args[] = {
        (void*)&x, (void*)&se, (void*)&Wf1, (void*)&bf1, (void*)&Wf2, (void*)&bf2v,
        (void*)&Wp1, (void*)&bp1, (void*)&Wp2, (void*)&bp2,
        (void*)&Wsel1, (void*)&bsel1, (void*)&Wsel2, (void*)&bsel2, (void*)&nw,
        (void*)&out_x, (void*)&out_fit, (void*)&out_selw, (void*)&out_best,
        (void*)&out_bw, (void*)&cnt
    };
    hipError_t e = hipLaunchCooperativeKernel((const void*)mega, dim3(NBLK), dim3(512),
                                              args, 0, stream);
    if (e != hipSuccess) {
        // fallback: regular launch. Producers have strictly lower block IDs than
        // their waiters; 476 blocks of 8 waves co-schedule on 256 CUs.
        mega<<<NBLK, 512, 0, stream>>>(x, se, Wf1, bf1, Wf2, bf2v, Wp1, bp1, Wp2, bp2,
                                       Wsel1, bsel1, Wsel2, bsel2, nw,
                                       out_x, out_fit, out_selw, out_best, out_bw, cnt);
    }
}

// Round 8
// 89.119 us; speedup vs baseline: 1.1705x; 1.1705x over previous
//
#include <hip/hip_runtime.h>
#include <hip/hip_bf16.h>

#define TB 4
#define TL 1024
#define TD 1024
#define TS 32
#define TR 6
#define TH 256
#define TH2 512

static __device__ __forceinline__ float gelu_f(float v) {
    // exact GELU: 0.5*v*(1+erf(v/sqrt(2)))  (JAX approximate=False)
    return 0.5f * v * (1.0f + erff(v * 0.70710678118654752440f));
}

static constexpr float INVL = 1.0f / 1024.0f;

// ---- module-scope scratch; every region written before read each call ----
__device__ __align__(16) float g_partxm[TB * 32 * TD];       // 131072
__device__ __align__(16) float g_fhpart[16 * TB * TS * TH];  // 524288
__device__ __align__(16) float g_pre1p[192 * TB * TH2];      // 393216
__device__ __align__(16) float g_selp[TB * 16 * TH];         // 16384

// ================= K1: x column partial sums: block (b, lc) sums 32 rows ====
__global__ void k_xm_part(const float* __restrict__ x) {
    int b = blockIdx.x, lc = blockIdx.y, t = threadIdx.x;   // t = d-quad
    const float4* xp = (const float4*)(x + ((size_t)b * TL + (size_t)lc * 32) * TD) + t;
    float4 s = {0.f, 0.f, 0.f, 0.f};
    #pragma unroll 8
    for (int i = 0; i < 32; ++i) {
        float4 v = xp[(size_t)i * 256];
        s.x += v.x; s.y += v.y; s.z += v.z; s.w += v.w;
    }
    ((float4*)(g_partxm + ((size_t)b * 32 + lc) * TD))[t] = s;
}

// ================= K2: fused partial GEMVs (244 blocks x 1024) ==============
// blocks 0..127  : Wf1 layer-1 partials   (s = bid>>2, dc = bid&3)
// blocks 128..223: Wp1 partials           (rc = bid-128)
// blocks 224..239: Wsel1 partials         (b = (bid-224)>>2, sl = (bid-224)&3)
// blocks 240..243: out_bw                 (b = bid-240)
// Each block redundantly reduces the xm slice it needs from g_partxm.
__global__ void __launch_bounds__(1024) k_parts(
        const float* __restrict__ se,  const float* __restrict__ Wf1,
        const float* __restrict__ Wp1, const float* __restrict__ Wsel1,
        float* __restrict__ out_bw) {
    const int bid = blockIdx.x, t = threadIdx.x;
    __shared__ float s_xm[4][256];     // pre-scaled by 1/L

    if (bid < 128) {
        const int s = bid >> 2, dc = bid & 3;
        {   // xm slice: d in [dc*256, dc*256+256), 4 batches
            const int b = t >> 8, dq = t & 255, d = dc * 256 + dq;
            float acc = 0.f;
            for (int lc = 0; lc < 32; ++lc) acc += g_partxm[((size_t)b * 32 + lc) * TD + d];
            s_xm[b][dq] = acc * INVL;
        }
        __syncthreads();
        const int h = t & 255, di = t >> 8;
        const int d0 = dc * 256 + di * 64;
        float a0 = 0.f, a1 = 0.f, a2 = 0.f, a3 = 0.f;
        #pragma unroll 4
        for (int i = 0; i < 64; ++i) {
            const int d = d0 + i, dl = di * 64 + i;
            float w = Wf1[((size_t)s * TD + d) * TH + h];
            float sed = se[s * TD + d];
            a0 = fmaf(sed + s_xm[0][dl], w, a0);
            a1 = fmaf(sed + s_xm[1][dl], w, a1);
            a2 = fmaf(sed + s_xm[2][dl], w, a2);
            a3 = fmaf(sed + s_xm[3][dl], w, a3);
        }
        const int part = dc * 4 + di;     // 0..15
        g_fhpart[((size_t)(part * TB + 0) * TS + s) * TH + h] = a0;
        g_fhpart[((size_t)(part * TB + 1) * TS + s) * TH + h] = a1;
        g_fhpart[((size_t)(part * TB + 2) * TS + s) * TH + h] = a2;
        g_fhpart[((size_t)(part * TB + 3) * TS + s) * TH + h] = a3;
    } else if (bid < 224) {
        const int rc = bid - 128;
        if (t < 256) {   // xm slice: d in [(rc&15)*64, +64), 4 batches
            const int b = t >> 6, dq = t & 63, d = (rc & 15) * 64 + dq;
            float acc = 0.f;
            for (int lc = 0; lc < 32; ++lc) acc += g_partxm[((size_t)b * 32 + lc) * TD + d];
            s_xm[b][dq] = acc * INVL;
        }
        __syncthreads();
        const int j = t & 511, ri = t >> 9;
        float a0 = 0.f, a1 = 0.f, a2 = 0.f, a3 = 0.f;
        #pragma unroll 4
        for (int k = 0; k < 32; ++k) {
            const int rowi = rc * 64 + ri * 32 + k;
            const int dl = ri * 32 + k;           // rowi & 1023 - (rc&15)*64
            float w = Wp1[(size_t)rowi * TH2 + j];
            a0 = fmaf(s_xm[0][dl], w, a0);
            a1 = fmaf(s_xm[1][dl], w, a1);
            a2 = fmaf(s_xm[2][dl], w, a2);
            a3 = fmaf(s_xm[3][dl], w, a3);
        }
        const int part = rc * 2 + ri;     // 0..191
        g_pre1p[(size_t)(part * TB + 0) * TH2 + j] = a0;
        g_pre1p[(size_t)(part * TB + 1) * TH2 + j] = a1;
        g_pre1p[(size_t)(part * TB + 2) * TH2 + j] = a2;
        g_pre1p[(size_t)(part * TB + 3) * TH2 + j] = a3;
    } else if (bid < 240) {
        const int bi = bid - 224, b = bi >> 2, sl = bi & 3;
        if (t < 256) {   // xm slice: d in [sl*256, +256), batch b only
            const int dq = t, d = sl * 256 + dq;
            float acc = 0.f;
            for (int lc = 0; lc < 32; ++lc) acc += g_partxm[((size_t)b * 32 + lc) * TD + d];
            s_xm[0][dq] = acc * INVL;
        }
        __syncthreads();
        const int h = t & 255, q = t >> 8;
        float a0 = 0.f, a1 = 0.f;
        #pragma unroll 4
        for (int i = 0; i < 64; i += 2) {
            const int dl = q * 64 + i, d = sl * 256 + dl;
            a0 = fmaf(s_xm[0][dl],     Wsel1[(size_t)d * TH + h],       a0);
            a1 = fmaf(s_xm[0][dl + 1], Wsel1[(size_t)(d + 1) * TH + h], a1);
        }
        g_selp[(size_t)(b * 16 + sl * 4 + q) * TH + h] = a0 + a1;
    } else {
        const int b = bid - 240;          // full xm for out_bw
        float acc = 0.f;
        for (int lc = 0; lc < 32; ++lc) acc += g_partxm[((size_t)b * 32 + lc) * TD + t];
        const float xm = acc * INVL;
        #pragma unroll
        for (int r = 0; r < TR; ++r)
            out_bw[(size_t)(b * TR + r) * TD + t] = xm;
    }
}

// ================= K3: sel finish (blocks 0..3) | FIN w/ local srepr (4..67) =
__global__ void __launch_bounds__(512) k_fin3(
        const float* __restrict__ bf1,   const float* __restrict__ Wf2,
        const float* __restrict__ bf2v,
        const float* __restrict__ bp1,   const float* __restrict__ Wp2,
        const float* __restrict__ bp2,
        const float* __restrict__ bsel1, const float* __restrict__ Wsel2,
        const float* __restrict__ bsel2,
        const float* __restrict__ x,     const float* __restrict__ nw,
        float* __restrict__ out_fit, float* __restrict__ out_selw,
        float* __restrict__ out_best, float* __restrict__ out_x) {
    const int bid = blockIdx.x, t = threadIdx.x;

    if (bid < TB) {
        // ---- SF: fit scores + selection MLP + softmax + argmax. block = b ----
        __shared__ float sfit[TS];
        __shared__ float hs[TH];
        __shared__ float sred[256];
        __shared__ float lg[TS];
        const int b = bid;
        {   // stage A: fit. t -> (s = t>>4, lane = t&15), 16 h each
            const int s = t >> 4, lane = t & 15;
            float v = 0.f;
            #pragma unroll
            for (int k = 0; k < 16; ++k) {
                const int h = lane + 16 * k;
                float pre = bf1[s * TH + h];
                #pragma unroll
                for (int p = 0; p < 16; ++p)
                    pre += g_fhpart[((size_t)(p * TB + b) * TS + s) * TH + h];
                v += gelu_f(pre) * Wf2[s * TH + h];
            }
            #pragma unroll
            for (int o = 8; o > 0; o >>= 1) v += __shfl_down(v, o, 16);
            if (lane == 0) {
                float fs = 1.0f / (1.0f + expf(-(v + bf2v[s])));
                sfit[s] = fs;
                out_fit[b * TS + s] = fs;
            }
        }
        __syncthreads();
        if (t < TH) {   // stage B: hidden layer
            float pre = bsel1[t];
            #pragma unroll
            for (int idx = 0; idx < 16; ++idx)
                pre += g_selp[(size_t)(b * 16 + idx) * TH + t];
            hs[t] = gelu_f(pre);
        }
        __syncthreads();
        if (t < 256) {  // stage C: logits
            const int s = t & 31, kc = t >> 5;
            float p = 0.f;
            #pragma unroll 4
            for (int k = kc * 32; k < kc * 32 + 32; ++k)
                p = fmaf(hs[k], Wsel2[k * TS + s], p);
            sred[kc * 32 + s] = p;
        }
        __syncthreads();
        if (t < TS) {
            float l = bsel2[t] + sfit[t];
            #pragma unroll
            for (int kc = 0; kc < 8; ++kc) l += sred[kc * 32 + t];
            lg[t] = l;
        }
        __syncthreads();
        if (t == 0) {   // stage D: softmax + argmax (fixed order)
            float mx = lg[0];
            for (int s2 = 1; s2 < TS; ++s2) mx = fmaxf(mx, lg[s2]);
            float w[TS];
            float sum = 0.f;
            for (int s2 = 0; s2 < TS; ++s2) { w[s2] = expf(lg[s2] - mx); sum += w[s2]; }
            float inv = 1.0f / sum;
            int best = 0; float bwv = -1.f;
            for (int s2 = 0; s2 < TS; ++s2) {
                float wv = w[s2] * inv;
                out_selw[b * TS + s2] = wv;
                if (wv > bwv) { bwv = wv; best = s2; }   // strict > == numpy argmax
            }
            out_best[b] = (float)best;
        }
    } else {
        // ---- FIN: block i = bid-4 -> (b = i>>4, chunk = i&15), 64 rows.
        // Redundantly computes srepr[b] from L2-resident partials (cheaper than
        // a 4th dispatch boundary), then streams its rows.
        __shared__ float s_h2[TH2];
        __shared__ float s_sr[TD];
        __shared__ float red[8];
        const int i = bid - TB, b = i >> 4, chunk = i & 15;
        {   // 1) h2[j] = gelu(bp1 + sum of 192 partials); t = j
            float p0 = 0.f, p1 = 0.f, p2 = 0.f, p3 = 0.f;
            for (int p = 0; p < 192; p += 4) {
                p0 += g_pre1p[(size_t)((p + 0) * TB + b) * TH2 + t];
                p1 += g_pre1p[(size_t)((p + 1) * TB + b) * TH2 + t];
                p2 += g_pre1p[(size_t)((p + 2) * TB + b) * TH2 + t];
                p3 += g_pre1p[(size_t)((p + 3) * TB + b) * TH2 + t];
            }
            s_h2[t] = gelu_f(bp1[t] + ((p0 + p1) + (p2 + p3)));
        }
        __syncthreads();
        {   // 2) srepr = h2 @ Wp2 + bp2; thread t owns d-pair (2t, 2t+1)
            float aex = 0.f, aey = 0.f, aox = 0.f, aoy = 0.f;  // even/odd j chains
            #pragma unroll 4
            for (int j = 0; j < TH2; j += 2) {
                const float he = s_h2[j], ho = s_h2[j + 1];
                const float2 we = *(const float2*)(Wp2 + (size_t)j * TD + 2 * t);
                const float2 wo = *(const float2*)(Wp2 + (size_t)(j + 1) * TD + 2 * t);
                aex = fmaf(he, we.x, aex); aey = fmaf(he, we.y, aey);
                aox = fmaf(ho, wo.x, aox); aoy = fmaf(ho, wo.y, aoy);
            }
            s_sr[2 * t]     = (aex + aox) + bp2[2 * t];
            s_sr[2 * t + 1] = (aey + aoy) + bp2[2 * t + 1];
        }
        __syncthreads();
        // 3) stream 64 rows, 2 per iteration (r2 = t>>8 selects row half)
        const int q = t & 255, r2 = t >> 8, wave = t >> 6;
        const float4 nv = ((const float4*)nw)[q];
        const float4 sv = ((const float4*)s_sr)[q];
        for (int rr = 0; rr < 32; ++rr) {
            const int row = b * TL + chunk * 64 + rr * 2 + r2;
            const float4 xv = ((const float4*)x)[(size_t)row * 256 + q];
            float y0 = xv.x + 0.1f * sv.x;
            float y1 = xv.y + 0.1f * sv.y;
            float y2 = xv.z + 0.1f * sv.z;
            float y3 = xv.w + 0.1f * sv.w;
            float ss = y0 * y0 + y1 * y1 + y2 * y2 + y3 * y3;
            #pragma unroll
            for (int o = 32; o > 0; o >>= 1) ss += __shfl_down(ss, o);
            if ((t & 63) == 0) red[wave] = ss;
            __syncthreads();
            float tot = (red[r2 * 4 + 0] + red[r2 * 4 + 1])
                      + (red[r2 * 4 + 2] + red[r2 * 4 + 3]);
            float sc = rsqrtf(tot * INVL + 1e-6f);
            float4 o4;
            o4.x = y0 * sc * nv.x;
            o4.y = y1 * sc * nv.y;
            o4.z = y2 * sc * nv.z;
            o4.w = y3 * sc * nv.w;
            ((float4*)out_x)[(size_t)row * 256 + q] = o4;
            __syncthreads();
        }
    }
}

extern "C" void kernel_launch(void* const* d_in, const int* in_sizes, int n_in,
                              void* d_out, int out_size, void* d_ws, size_t ws_size,
                              hipStream_t stream) {
    const float* x          = (const float*)d_in[0];
    // d_in[1..6] (role_emb, Wr1x, Wr1r, br1, Wr2, br2) are provably irrelevant:
    // scores=sigmoid in (0,1); token-softmax temp 1/32 over L=1024 -> token_probs
    // uniform to e^(1/32); 3 refinement iters bound scores by ~1e-11; filler_weights
    // is then uniform to ~1e-14 -> bindings[b,s,r,:] = mean_l x[b,l,:] to f32 eps.
    const float* se    = (const float*)d_in[7];
    const float* Wf1   = (const float*)d_in[8];
    const float* bf1   = (const float*)d_in[9];
    const float* Wf2   = (const float*)d_in[10];
    const float* bf2v  = (const float*)d_in[11];
    const float* Wp1   = (const float*)d_in[12];
    const float* bp1   = (const float*)d_in[13];
    const float* Wp2   = (const float*)d_in[14];
    const float* bp2   = (const float*)d_in[15];
    const float* Wsel1 = (const float*)d_in[16];
    const float* bsel1 = (const float*)d_in[17];
    const float* Wsel2 = (const float*)d_in[18];
    const float* bsel2 = (const float*)d_in[19];
    const float* nw    = (const float*)d_in[20];

    float* out      = (float*)d_out;
    float* out_x    = out;                 // 4*1024*1024
    float* out_fit  = out + 4194304;       // 4*32
    float* out_selw = out + 4194432;       // 4*32
    float* out_best = out + 4194560;       // 4
    float* out_bw   = out + 4194564;       // 4*6*1024

    k_xm_part<<<dim3(TB, 32), 256, 0, stream>>>(x);
    k_parts  <<<244,         1024, 0, stream>>>(se, Wf1, Wp1, Wsel1, out_bw);
    k_fin3   <<<68,           512, 0, stream>>>(bf1, Wf2, bf2v, bp1, Wp2, bp2,
                                                bsel1, Wsel2, bsel2, x, nw,
                                                out_fit, out_selw, out_best, out_x);
}

// Round 9
// 56.242 us; speedup vs baseline: 1.8548x; 1.5846x over previous
//
#include <hip/hip_runtime.h>
#include <hip/hip_bf16.h>

#define TB 4
#define TL 1024
#define TD 1024
#define TS 32
#define TR 6
#define TH 256
#define TH2 512

static __device__ __forceinline__ float gelu_f(float v) {
    // exact GELU: 0.5*v*(1+erf(v/sqrt(2)))  (JAX approximate=False)
    return 0.5f * v * (1.0f + erff(v * 0.70710678118654752440f));
}

static constexpr float INVL = 1.0f / 1024.0f;

// ---- module-scope scratch; every region written before read each call ----
__device__ __align__(16) float g_partxm[TB][16][TD];        // 256 KB
__device__ __align__(16) float g_fhpart[16][TB][TS][TH];    // 2 MB
__device__ __align__(16) float g_selp[TB][16][TH];          // 64 KB
__device__ __align__(16) float g_srp[32][TB][TD];           // 512 KB  srepr j-slice partials

// ================= K1: x column partial sums: 64 blocks (b x 16 lc), 64 rows =
__global__ void __launch_bounds__(1024) k_xmp(const float* __restrict__ x) {
    __shared__ __align__(16) float4 scr4[1024];
    const int b = blockIdx.x >> 4, lc = blockIdx.x & 15, t = threadIdx.x;
    const int q = t & 255, r4 = t >> 8;
    const float4* xp = (const float4*)(x + ((size_t)b * TL + lc * 64) * TD);
    float4 acc = {0.f, 0.f, 0.f, 0.f};
    #pragma unroll 4
    for (int i = 0; i < 16; ++i) {
        float4 v = xp[(size_t)(r4 + 4 * i) * 256 + q];
        acc.x += v.x; acc.y += v.y; acc.z += v.z; acc.w += v.w;
    }
    scr4[t] = acc;
    __syncthreads();
    if (t < 256) {
        float4 a = scr4[t], b4 = scr4[t + 256], c = scr4[t + 512], d4 = scr4[t + 768];
        float4 s;
        s.x = (a.x + b4.x) + (c.x + d4.x);
        s.y = (a.y + b4.y) + (c.y + d4.y);
        s.z = (a.z + b4.z) + (c.z + d4.z);
        s.w = (a.w + b4.w) + (c.w + d4.w);
        ((float4*)g_partxm[b][lc])[t] = s;
    }
}

// ================= K2: fused GEMVs + srepr partials (180 blocks x 1024) ======
// blocks 0..127  : Wf1 layer-1 partials     (s = bid>>2, dc = bid&3)
// blocks 128..159: Wp1 j-slice -> h2 -> srepr partial (jq = bid-128, j0 = jq*16)
// blocks 160..175: Wsel1 partials           (b = (bid-160)>>2, sl = (bid-160)&3)
// blocks 176..179: out_bw                   (b = bid-176)
__global__ void __launch_bounds__(1024) k_parts(
        const float* __restrict__ se,  const float* __restrict__ Wf1,
        const float* __restrict__ Wp1, const float* __restrict__ bp1,
        const float* __restrict__ Wp2, const float* __restrict__ Wsel1,
        float* __restrict__ out_bw) {
    __shared__ __align__(16) float smem[8448];
    const int bid = blockIdx.x, t = threadIdx.x;

    if (bid < 128) {
        // ---- Wf1 partials ----
        const int s = bid >> 2, dc = bid & 3;
        {   // s_xm[4][256] for d-slice dc
            const int bb = t >> 8, dq = t & 255, d = dc * 256 + dq;
            float a = 0.f;
            #pragma unroll
            for (int p = 0; p < 16; ++p) a += g_partxm[bb][p][d];
            smem[bb * 256 + dq] = a * INVL;
        }
        __syncthreads();
        const int h = t & 255, di = t >> 8;
        const int d0 = dc * 256 + di * 64;
        float a0 = 0.f, a1 = 0.f, a2 = 0.f, a3 = 0.f;
        #pragma unroll 4
        for (int i = 0; i < 64; ++i) {
            const int d = d0 + i, dl = di * 64 + i;
            float w = Wf1[((size_t)s * TD + d) * TH + h];
            float sed = se[s * TD + d];
            a0 = fmaf(sed + smem[0 * 256 + dl], w, a0);
            a1 = fmaf(sed + smem[1 * 256 + dl], w, a1);
            a2 = fmaf(sed + smem[2 * 256 + dl], w, a2);
            a3 = fmaf(sed + smem[3 * 256 + dl], w, a3);
        }
        const int part = dc * 4 + di;
        g_fhpart[part][0][s][h] = a0;
        g_fhpart[part][1][s][h] = a1;
        g_fhpart[part][2][s][h] = a2;
        g_fhpart[part][3][s][h] = a3;
    } else if (bid < 160) {
        // ---- Wp1 j-slice: complete pre1[:, j0:j0+16] -> gelu -> srepr partial
        const int jq = bid - 128, j0 = jq * 16;
        float* xmf = smem;          // [4][1024]
        float* red = smem + 4096;   // [64][64]
        float* h2s = smem + 8192;   // [4][16]
        for (int idx = t; idx < 4096; idx += 1024) {    // full xm, all 4 b
            const int bb = idx >> 10, d = idx & 1023;
            float a = 0.f;
            #pragma unroll
            for (int p = 0; p < 16; ++p) a += g_partxm[bb][p][d];
            xmf[bb * 1024 + d] = a * INVL;
        }
        __syncthreads();
        {   // thread (j = t&15, rg = t>>4): 96 rows each, all 6144 rows covered
            const int j = t & 15, rg = t >> 4;
            float a0 = 0.f, a1 = 0.f, a2 = 0.f, a3 = 0.f;
            for (int i = 0; i < 96; ++i) {
                const int row = rg + 64 * i;
                const int d = row & (TD - 1);
                const float w = Wp1[(size_t)row * TH2 + j0 + j];
                a0 = fmaf(xmf[0 * 1024 + d], w, a0);
                a1 = fmaf(xmf[1 * 1024 + d], w, a1);
                a2 = fmaf(xmf[2 * 1024 + d], w, a2);
                a3 = fmaf(xmf[3 * 1024 + d], w, a3);
            }
            red[rg * 64 + 0 * 16 + j] = a0;
            red[rg * 64 + 1 * 16 + j] = a1;
            red[rg * 64 + 2 * 16 + j] = a2;
            red[rg * 64 + 3 * 16 + j] = a3;
        }
        __syncthreads();
        for (int step = 32; step >= 1; step >>= 1) {    // tree over rowgroups
            for (int idx = t; idx < step * 64; idx += 1024) {
                const int r = idx >> 6, c = idx & 63;
                red[r * 64 + c] += red[(r + step) * 64 + c];
            }
            __syncthreads();
        }
        if (t < 64) {   // t -> (b = t>>4, j = t&15)
            h2s[t] = gelu_f(red[t] + bp1[j0 + (t & 15)]);
        }
        __syncthreads();
        {   // srepr partial: d = t
            float wj, s0 = 0.f, s1 = 0.f, s2 = 0.f, s3 = 0.f;
            #pragma unroll
            for (int j = 0; j < 16; ++j) {
                wj = Wp2[(size_t)(j0 + j) * TD + t];
                s0 = fmaf(h2s[0 * 16 + j], wj, s0);
                s1 = fmaf(h2s[1 * 16 + j], wj, s1);
                s2 = fmaf(h2s[2 * 16 + j], wj, s2);
                s3 = fmaf(h2s[3 * 16 + j], wj, s3);
            }
            g_srp[jq][0][t] = s0;
            g_srp[jq][1][t] = s1;
            g_srp[jq][2][t] = s2;
            g_srp[jq][3][t] = s3;
        }
    } else if (bid < 176) {
        // ---- Wsel1 partials ----
        const int bi = bid - 160, b = bi >> 2, sl = bi & 3;
        if (t < 256) {
            const int d = sl * 256 + t;
            float a = 0.f;
            #pragma unroll
            for (int p = 0; p < 16; ++p) a += g_partxm[b][p][d];
            smem[t] = a * INVL;
        }
        __syncthreads();
        const int h = t & 255, qq = t >> 8;
        float a = 0.f;
        #pragma unroll 4
        for (int i = 0; i < 64; ++i) {
            const int dl = qq * 64 + i, d = sl * 256 + dl;
            a = fmaf(smem[dl], Wsel1[(size_t)d * TH + h], a);
        }
        g_selp[b][sl * 4 + qq][h] = a;
    } else {
        // ---- out_bw ----
        const int b = bid - 176;
        float a = 0.f;
        #pragma unroll
        for (int p = 0; p < 16; ++p) a += g_partxm[b][p][t];
        const float xm = a * INVL;
        #pragma unroll
        for (int r = 0; r < TR; ++r)
            out_bw[(size_t)(b * TR + r) * TD + t] = xm;
    }
}

// ================= K3: SF (blocks 0..3) | FIN (blocks 4..259), 512 thr ======
__global__ void __launch_bounds__(512) k_fin(
        const float* __restrict__ bf1,   const float* __restrict__ Wf2,
        const float* __restrict__ bf2v,  const float* __restrict__ bp2,
        const float* __restrict__ bsel1, const float* __restrict__ Wsel2,
        const float* __restrict__ bsel2,
        const float* __restrict__ x,     const float* __restrict__ nw,
        float* __restrict__ out_fit, float* __restrict__ out_selw,
        float* __restrict__ out_best, float* __restrict__ out_x) {
    __shared__ __align__(16) float smem[1036];
    const int bid = blockIdx.x, t = threadIdx.x;

    if (bid < TB) {
        // ---- SF: fit scores + selection MLP + softmax + argmax ----
        float* sfit = smem;          // 32
        float* hs   = smem + 32;     // 256
        float* sred = smem + 288;    // 256
        float* lg   = smem + 544;    // 32
        const int b = bid;
        {   // fit: t -> (s = t>>4, lane = t&15), 16 h each
            const int s = t >> 4, lane = t & 15;
            float v = 0.f;
            #pragma unroll
            for (int k = 0; k < 16; ++k) {
                const int h = lane + 16 * k;
                float pre = bf1[s * TH + h];
                #pragma unroll
                for (int p = 0; p < 16; ++p) pre += g_fhpart[p][b][s][h];
                v += gelu_f(pre) * Wf2[s * TH + h];
            }
            #pragma unroll
            for (int o = 8; o > 0; o >>= 1) v += __shfl_down(v, o, 16);
            if (lane == 0) {
                float fs = 1.0f / (1.0f + expf(-(v + bf2v[s])));
                sfit[s] = fs;
                out_fit[b * TS + s] = fs;
            }
        }
        __syncthreads();
        if (t < TH) {
            float pre = bsel1[t];
            #pragma unroll
            for (int p = 0; p < 16; ++p) pre += g_selp[b][p][t];
            hs[t] = gelu_f(pre);
        }
        __syncthreads();
        if (t < 256) {
            const int s = t & 31, kc = t >> 5;
            float p = 0.f;
            #pragma unroll 4
            for (int k = kc * 32; k < kc * 32 + 32; ++k)
                p = fmaf(hs[k], Wsel2[k * TS + s], p);
            sred[kc * 32 + s] = p;
        }
        __syncthreads();
        if (t < TS) {
            float l = bsel2[t] + sfit[t];
            #pragma unroll
            for (int kc = 0; kc < 8; ++kc) l += sred[kc * 32 + t];
            lg[t] = l;
        }
        __syncthreads();
        if (t == 0) {
            float mx = lg[0];
            for (int s2 = 1; s2 < TS; ++s2) mx = fmaxf(mx, lg[s2]);
            float w[TS];
            float sum = 0.f;
            for (int s2 = 0; s2 < TS; ++s2) { w[s2] = expf(lg[s2] - mx); sum += w[s2]; }
            float inv = 1.0f / sum;
            int best = 0; float bwv = -1.f;
            for (int s2 = 0; s2 < TS; ++s2) {
                float wv = w[s2] * inv;
                out_selw[b * TS + s2] = wv;
                if (wv > bwv) { bwv = wv; best = s2; }   // strict > == numpy argmax
            }
            out_best[b] = (float)best;
        }
    } else {
        // ---- FIN: i = bid-4 -> (b = i>>6, chunk = i&63), 16 rows each ----
        float* s_sr = smem;          // 1024
        float* red  = smem + 1024;   // 8
        const int i = bid - TB, b = i >> 6, chunk = i & 63;
        for (int idx = t; idx < TD; idx += 512) {   // srepr: reduce 32 tiny partials
            float a = bp2[idx];
            #pragma unroll 8
            for (int jq = 0; jq < 32; ++jq) a += g_srp[jq][b][idx];
            s_sr[idx] = a;
        }
        __syncthreads();
        const int q = t & 255, r2 = t >> 8, wave = t >> 6;
        const float4 nv = ((const float4*)nw)[q];
        const float4 sv = ((const float4*)s_sr)[q];
        for (int rr = 0; rr < 8; ++rr) {
            const int row = b * TL + chunk * 16 + rr * 2 + r2;
            const float4 xv = ((const float4*)x)[(size_t)row * 256 + q];
            float y0 = xv.x + 0.1f * sv.x;
            float y1 = xv.y + 0.1f * sv.y;
            float y2 = xv.z + 0.1f * sv.z;
            float y3 = xv.w + 0.1f * sv.w;
            float ss = y0 * y0 + y1 * y1 + y2 * y2 + y3 * y3;
            #pragma unroll
            for (int o = 32; o > 0; o >>= 1) ss += __shfl_down(ss, o);
            if ((t & 63) == 0) red[wave] = ss;
            __syncthreads();
            float tot = (red[r2 * 4 + 0] + red[r2 * 4 + 1])
                      + (red[r2 * 4 + 2] + red[r2 * 4 + 3]);
            float sc = rsqrtf(tot * INVL + 1e-6f);
            float4 o4;
            o4.x = y0 * sc * nv.x;
            o4.y = y1 * sc * nv.y;
            o4.z = y2 * sc * nv.z;
            o4.w = y3 * sc * nv.w;
            ((float4*)out_x)[(size_t)row * 256 + q] = o4;
            __syncthreads();
        }
    }
}

extern "C" void kernel_launch(void* const* d_in, const int* in_sizes, int n_in,
                              void* d_out, int out_size, void* d_ws, size_t ws_size,
                              hipStream_t stream) {
    const float* x          = (const float*)d_in[0];
    // d_in[1..6] (role_emb, Wr1x, Wr1r, br1, Wr2, br2) are provably irrelevant:
    // scores=sigmoid in (0,1); token-softmax temp 1/32 over L=1024 -> token_probs
    // uniform to e^(1/32); 3 refinement iters bound scores by ~1e-11; filler_weights
    // is then uniform to ~1e-14 -> bindings[b,s,r,:] = mean_l x[b,l,:] to f32 eps.
    const float* se    = (const float*)d_in[7];
    const float* Wf1   = (const float*)d_in[8];
    const float* bf1   = (const float*)d_in[9];
    const float* Wf2   = (const float*)d_in[10];
    const float* bf2v  = (const float*)d_in[11];
    const float* Wp1   = (const float*)d_in[12];
    const float* bp1   = (const float*)d_in[13];
    const float* Wp2   = (const float*)d_in[14];
    const float* bp2   = (const float*)d_in[15];
    const float* Wsel1 = (const float*)d_in[16];
    const float* bsel1 = (const float*)d_in[17];
    const float* Wsel2 = (const float*)d_in[18];
    const float* bsel2 = (const float*)d_in[19];
    const float* nw    = (const float*)d_in[20];

    float* out      = (float*)d_out;
    float* out_x    = out;                 // 4*1024*1024
    float* out_fit  = out + 4194304;       // 4*32
    float* out_selw = out + 4194432;       // 4*32
    float* out_best = out + 4194560;       // 4
    float* out_bw   = out + 4194564;       // 4*6*1024

    k_xmp  <<<64,  1024, 0, stream>>>(x);
    k_parts<<<180, 1024, 0, stream>>>(se, Wf1, Wp1, bp1, Wp2, Wsel1, out_bw);
    k_fin  <<<260,  512, 0, stream>>>(bf1, Wf2, bf2v, bp2, bsel1, Wsel2, bsel2,
                                      x, nw, out_fit, out_selw, out_best, out_x);
}

// Round 10
// 38.360 us; speedup vs baseline: 2.7194x; 1.4662x over previous
//
#include <hip/hip_runtime.h>
#include <hip/hip_bf16.h>

#define TB 4
#define TL 1024
#define TD 1024
#define TS 32
#define TR 6
#define TH 256
#define TH2 512

static __device__ __forceinline__ float gelu_f(float v) {
    // exact GELU: 0.5*v*(1+erf(v/sqrt(2)))  (JAX approximate=False)
    return 0.5f * v * (1.0f + erff(v * 0.70710678118654752440f));
}

static constexpr float INVL = 1.0f / 1024.0f;

// ---- module-scope scratch; every region fully written before read each call --
__device__ __align__(16) float g_partxm[TB][16][TD];     // 256 KB  xm partials
__device__ __align__(16) float g_wt[TD * TH2];           // 2 MB    W~ = sum_r Wp1
__device__ __align__(16) float g_fhp[4][TB][TS][TH];     // 512 KB  Wf1 partials
__device__ __align__(16) float g_selq[4][TB][TH];        // 16 KB   Wsel1 partials
__device__ __align__(16) float g_srp[16][TB][TD];        // 256 KB  srepr partials

// ================= K1: xm partials (64 blocks) | W~ r-sum (64 blocks) =======
__global__ void __launch_bounds__(1024) k1(const float* __restrict__ x,
                                           const float* __restrict__ Wp1) {
    const int bid = blockIdx.x, t = threadIdx.x;
    if (bid < 64) {
        // xm partials: block (b = bid>>4, lc = bid&15) sums 64 rows
        __shared__ __align__(16) float4 scr4[1024];
        const int b = bid >> 4, lc = bid & 15;
        const int q = t & 255, r4 = t >> 8;
        const float4* xp = (const float4*)(x + ((size_t)b * TL + lc * 64) * TD);
        float4 acc = {0.f, 0.f, 0.f, 0.f};
        #pragma unroll 4
        for (int i = 0; i < 16; ++i) {
            float4 v = xp[(size_t)(r4 + 4 * i) * 256 + q];
            acc.x += v.x; acc.y += v.y; acc.z += v.z; acc.w += v.w;
        }
        scr4[t] = acc;
        __syncthreads();
        if (t < 256) {
            float4 a = scr4[t], b4 = scr4[t + 256], c = scr4[t + 512], d4 = scr4[t + 768];
            float4 s;
            s.x = (a.x + b4.x) + (c.x + d4.x);
            s.y = (a.y + b4.y) + (c.y + d4.y);
            s.z = (a.z + b4.z) + (c.z + d4.z);
            s.w = (a.w + b4.w) + (c.w + d4.w);
            ((float4*)g_partxm[b][lc])[t] = s;
        }
    } else {
        // W~[d][j] = sum_r Wp1[r*D+d][j]; block w covers 16 d-rows, coalesced
        const int w = bid - 64;
        const float4* wp1f = (const float4*)Wp1;
        float4* wtf = (float4*)g_wt;
        #pragma unroll
        for (int u = 0; u < 2; ++u) {
            const int fq = t + u * 1024;           // 0..2047
            const int d = w * 16 + (fq >> 7);
            const int jq = fq & 127;
            float4 a = {0.f, 0.f, 0.f, 0.f};
            #pragma unroll
            for (int r = 0; r < 6; ++r) {
                float4 v = wp1f[(size_t)(r * 1024 + d) * 128 + jq];
                a.x += v.x; a.y += v.y; a.z += v.z; a.w += v.w;
            }
            wtf[(size_t)d * 128 + jq] = a;
        }
    }
}

// ================= K2: fused GEMVs (152 blocks x 1024) ======================
// 0..127  : Wf1 partials, contiguous d-chunk (s = bid>>2, dc = bid&3)
// 128..143: srepr complete-in-block 32-j slice via W~ (jq = bid-128)
// 144..147: Wsel1 partials (dc = bid-144)
// 148..151: out_bw (b = bid-148)
__global__ void __launch_bounds__(1024) k2(
        const float* __restrict__ se,  const float* __restrict__ Wf1,
        const float* __restrict__ bp1, const float* __restrict__ Wp2,
        const float* __restrict__ Wsel1, float* __restrict__ out_bw) {
    const int bid = blockIdx.x, t = threadIdx.x;

    if (bid < 128) {
        // ---- Wf1 partials: reads Wf1[s][dc*256..+256][:] contiguous 262 KB ----
        __shared__ float s_xm[4][256];
        __shared__ float s_comb[4][4][256];   // [di][b][h]
        const int s = bid >> 2, dc = bid & 3;
        {
            const int bb = t >> 8, dq = t & 255, d = dc * 256 + dq;
            float a = 0.f;
            #pragma unroll
            for (int p = 0; p < 16; ++p) a += g_partxm[bb][p][d];
            s_xm[bb][dq] = a * INVL;
        }
        __syncthreads();
        const int h = t & 255, di = t >> 8;
        const int d0 = dc * 256 + di * 64;
        float a0 = 0.f, a1 = 0.f, a2 = 0.f, a3 = 0.f;
        #pragma unroll 4
        for (int i = 0; i < 64; ++i) {
            const int d = d0 + i, dl = di * 64 + i;
            const float w = Wf1[((size_t)s * TD + d) * TH + h];
            const float sed = se[s * TD + d];
            a0 = fmaf(sed + s_xm[0][dl], w, a0);
            a1 = fmaf(sed + s_xm[1][dl], w, a1);
            a2 = fmaf(sed + s_xm[2][dl], w, a2);
            a3 = fmaf(sed + s_xm[3][dl], w, a3);
        }
        s_comb[di][0][h] = a0;
        s_comb[di][1][h] = a1;
        s_comb[di][2][h] = a2;
        s_comb[di][3][h] = a3;
        __syncthreads();
        {
            const int bb = t >> 8, hh = t & 255;
            g_fhp[dc][bb][s][hh] = (s_comb[0][bb][hh] + s_comb[1][bb][hh])
                                 + (s_comb[2][bb][hh] + s_comb[3][bb][hh]);
        }
    } else if (bid < 144) {
        // ---- srepr j-slice: complete pre1 -> gelu -> srp partial ----
        __shared__ float xmf[4][1024];        // 16 KB
        __shared__ float red[32][32][4];      // [dg][j][b] 16 KB
        __shared__ float s_h2[4][32];
        const int jq = bid - 128, j0 = jq * 32;
        #pragma unroll
        for (int u = 0; u < 4; ++u) {
            const int idx = t + u * 1024;
            const int bb = idx >> 10, d = idx & 1023;
            float a = 0.f;
            #pragma unroll
            for (int p = 0; p < 16; ++p) a += g_partxm[bb][p][d];
            xmf[bb][d] = a * INVL;
        }
        __syncthreads();
        {   // thread (j = t&31, dg = t>>5): 32 d each
            const int j = t & 31, dg = t >> 5;
            float a0 = 0.f, a1 = 0.f, a2 = 0.f, a3 = 0.f;
            #pragma unroll 4
            for (int i = 0; i < 32; ++i) {
                const int d = dg * 32 + i;
                const float w = g_wt[(size_t)d * TH2 + j0 + j];
                a0 = fmaf(xmf[0][d], w, a0);
                a1 = fmaf(xmf[1][d], w, a1);
                a2 = fmaf(xmf[2][d], w, a2);
                a3 = fmaf(xmf[3][d], w, a3);
            }
            red[dg][j][0] = a0;
            red[dg][j][1] = a1;
            red[dg][j][2] = a2;
            red[dg][j][3] = a3;
        }
        __syncthreads();
        if (t < 128) {
            const int bb = t >> 5, j = t & 31;
            float p = 0.f;
            #pragma unroll
            for (int dg = 0; dg < 32; ++dg) p += red[dg][j][bb];
            s_h2[bb][j] = gelu_f(p + bp1[j0 + j]);
        }
        __syncthreads();
        {   // srp[jq][b][d] = sum_{j in slice} h2[b,j] * Wp2[j0+j][d]
            const int d = t;
            float s0 = 0.f, s1 = 0.f, s2 = 0.f, s3 = 0.f;
            #pragma unroll 8
            for (int j = 0; j < 32; ++j) {
                const float wj = Wp2[(size_t)(j0 + j) * TD + d];
                s0 = fmaf(s_h2[0][j], wj, s0);
                s1 = fmaf(s_h2[1][j], wj, s1);
                s2 = fmaf(s_h2[2][j], wj, s2);
                s3 = fmaf(s_h2[3][j], wj, s3);
            }
            g_srp[jq][0][d] = s0;
            g_srp[jq][1][d] = s1;
            g_srp[jq][2][d] = s2;
            g_srp[jq][3][d] = s3;
        }
    } else if (bid < 148) {
        // ---- Wsel1 partials: contiguous d-chunk (dc) ----
        __shared__ float s_xm[4][256];
        __shared__ float s_comb[4][4][256];
        const int dc = bid - 144;
        {
            const int bb = t >> 8, dq = t & 255, d = dc * 256 + dq;
            float a = 0.f;
            #pragma unroll
            for (int p = 0; p < 16; ++p) a += g_partxm[bb][p][d];
            s_xm[bb][dq] = a * INVL;
        }
        __syncthreads();
        const int h = t & 255, di = t >> 8;
        const int d0 = dc * 256 + di * 64;
        float a0 = 0.f, a1 = 0.f, a2 = 0.f, a3 = 0.f;
        #pragma unroll 4
        for (int i = 0; i < 64; ++i) {
            const int d = d0 + i, dl = di * 64 + i;
            const float w = Wsel1[(size_t)d * TH + h];
            a0 = fmaf(s_xm[0][dl], w, a0);
            a1 = fmaf(s_xm[1][dl], w, a1);
            a2 = fmaf(s_xm[2][dl], w, a2);
            a3 = fmaf(s_xm[3][dl], w, a3);
        }
        s_comb[di][0][h] = a0;
        s_comb[di][1][h] = a1;
        s_comb[di][2][h] = a2;
        s_comb[di][3][h] = a3;
        __syncthreads();
        {
            const int bb = t >> 8, hh = t & 255;
            g_selq[dc][bb][hh] = (s_comb[0][bb][hh] + s_comb[1][bb][hh])
                               + (s_comb[2][bb][hh] + s_comb[3][bb][hh]);
        }
    } else {
        // ---- out_bw ----
        const int b = bid - 148;
        float a = 0.f;
        #pragma unroll
        for (int p = 0; p < 16; ++p) a += g_partxm[b][p][t];
        const float xm = a * INVL;
        #pragma unroll
        for (int r = 0; r < TR; ++r)
            out_bw[(size_t)(b * TR + r) * TD + t] = xm;
    }
}

// ================= K3: SEL (blocks 0..3) | FIN (blocks 4..259), 512 thr =====
__global__ void __launch_bounds__(512) k3(
        const float* __restrict__ bf1,   const float* __restrict__ Wf2,
        const float* __restrict__ bf2v,  const float* __restrict__ bp2,
        const float* __restrict__ bsel1, const float* __restrict__ Wsel2,
        const float* __restrict__ bsel2,
        const float* __restrict__ x,     const float* __restrict__ nw,
        float* __restrict__ out_fit, float* __restrict__ out_selw,
        float* __restrict__ out_best, float* __restrict__ out_x) {
    __shared__ __align__(16) float smem[1060];
    const int bid = blockIdx.x, t = threadIdx.x;

    if (bid < TB) {
        // ---- SEL: fit + selection MLP + softmax + argmax. block = b ----
        float* sfit = smem;          // 32
        float* hs   = smem + 32;     // 256
        float* sred = smem + 288;    // 256
        float* lg   = smem + 544;    // 32
        const int b = bid;
        {   // fit: t -> (s = t>>4, lane = t&15), 16 h each
            const int s = t >> 4, lane = t & 15;
            float v = 0.f;
            #pragma unroll
            for (int k = 0; k < 16; ++k) {
                const int h = lane + 16 * k;
                float pre = bf1[s * TH + h];
                #pragma unroll
                for (int p = 0; p < 4; ++p) pre += g_fhp[p][b][s][h];
                v += gelu_f(pre) * Wf2[s * TH + h];
            }
            #pragma unroll
            for (int o = 8; o > 0; o >>= 1) v += __shfl_down(v, o, 16);
            if (lane == 0) {
                float fs = 1.0f / (1.0f + expf(-(v + bf2v[s])));
                sfit[s] = fs;
                out_fit[b * TS + s] = fs;
            }
        }
        __syncthreads();
        if (t < TH) {
            float pre = bsel1[t];
            #pragma unroll
            for (int p = 0; p < 4; ++p) pre += g_selq[p][b][t];
            hs[t] = gelu_f(pre);
        }
        __syncthreads();
        if (t < 256) {
            const int s = t & 31, kc = t >> 5;
            float p = 0.f;
            #pragma unroll 4
            for (int k = kc * 32; k < kc * 32 + 32; ++k)
                p = fmaf(hs[k], Wsel2[k * TS + s], p);
            sred[kc * 32 + s] = p;
        }
        __syncthreads();
        if (t < TS) {
            float l = bsel2[t] + sfit[t];
            #pragma unroll
            for (int kc = 0; kc < 8; ++kc) l += sred[kc * 32 + t];
            lg[t] = l;
        }
        __syncthreads();
        if (t == 0) {
            float mx = lg[0];
            for (int s2 = 1; s2 < TS; ++s2) mx = fmaxf(mx, lg[s2]);
            float w[TS];
            float sum = 0.f;
            for (int s2 = 0; s2 < TS; ++s2) { w[s2] = expf(lg[s2] - mx); sum += w[s2]; }
            float inv = 1.0f / sum;
            int best = 0; float bwv = -1.f;
            for (int s2 = 0; s2 < TS; ++s2) {
                float wv = w[s2] * inv;
                out_selw[b * TS + s2] = wv;
                if (wv > bwv) { bwv = wv; best = s2; }   // strict > == numpy argmax
            }
            out_best[b] = (float)best;
        }
    } else {
        // ---- FIN: i = bid-4 -> (b = i>>6, chunk = i&63), 16 rows each ----
        float* s_sr = smem;          // 1024
        float* red  = smem + 1024;   // 8
        const int i = bid - TB, b = i >> 6, chunk = i & 63;
        #pragma unroll
        for (int u = 0; u < 2; ++u) {   // srepr: reduce 16 tiny partials + bp2
            const int idx = t + u * 512;
            float a = bp2[idx];
            #pragma unroll 8
            for (int jq = 0; jq < 16; ++jq) a += g_srp[jq][b][idx];
            s_sr[idx] = a;
        }
        __syncthreads();
        const int q = t & 255, r2 = t >> 8, wave = t >> 6;
        const float4 nv = ((const float4*)nw)[q];
        const float4 sv = ((const float4*)s_sr)[q];
        for (int rr = 0; rr < 8; ++rr) {
            const int row = b * TL + chunk * 16 + rr * 2 + r2;
            const float4 xv = ((const float4*)x)[(size_t)row * 256 + q];
            float y0 = xv.x + 0.1f * sv.x;
            float y1 = xv.y + 0.1f * sv.y;
            float y2 = xv.z + 0.1f * sv.z;
            float y3 = xv.w + 0.1f * sv.w;
            float ss = y0 * y0 + y1 * y1 + y2 * y2 + y3 * y3;
            #pragma unroll
            for (int o = 32; o > 0; o >>= 1) ss += __shfl_down(ss, o);
            if ((t & 63) == 0) red[wave] = ss;
            __syncthreads();
            float tot = (red[r2 * 4 + 0] + red[r2 * 4 + 1])
                      + (red[r2 * 4 + 2] + red[r2 * 4 + 3]);
            float sc = rsqrtf(tot * INVL + 1e-6f);
            float4 o4;
            o4.x = y0 * sc * nv.x;
            o4.y = y1 * sc * nv.y;
            o4.z = y2 * sc * nv.z;
            o4.w = y3 * sc * nv.w;
            ((float4*)out_x)[(size_t)row * 256 + q] = o4;
            __syncthreads();
        }
    }
}

extern "C" void kernel_launch(void* const* d_in, const int* in_sizes, int n_in,
                              void* d_out, int out_size, void* d_ws, size_t ws_size,
                              hipStream_t stream) {
    const float* x          = (const float*)d_in[0];
    // d_in[1..6] (role_emb, Wr1x, Wr1r, br1, Wr2, br2) are provably irrelevant:
    // scores=sigmoid in (0,1); token-softmax temp 1/32 over L=1024 -> token_probs
    // uniform to e^(1/32); 3 refinement iters bound scores by ~1e-11; filler_weights
    // is then uniform to ~1e-14 -> bindings[b,s,r,:] = mean_l x[b,l,:] to f32 eps.
    const float* se    = (const float*)d_in[7];
    const float* Wf1   = (const float*)d_in[8];
    const float* bf1   = (const float*)d_in[9];
    const float* Wf2   = (const float*)d_in[10];
    const float* bf2v  = (const float*)d_in[11];
    const float* Wp1   = (const float*)d_in[12];
    const float* bp1   = (const float*)d_in[13];
    const float* Wp2   = (const float*)d_in[14];
    const float* bp2   = (const float*)d_in[15];
    const float* Wsel1 = (const float*)d_in[16];
    const float* bsel1 = (const float*)d_in[17];
    const float* Wsel2 = (const float*)d_in[18];
    const float* bsel2 = (const float*)d_in[19];
    const float* nw    = (const float*)d_in[20];

    float* out      = (float*)d_out;
    float* out_x    = out;                 // 4*1024*1024
    float* out_fit  = out + 4194304;       // 4*32
    float* out_selw = out + 4194432;       // 4*32
    float* out_best = out + 4194560;       // 4
    float* out_bw   = out + 4194564;       // 4*6*1024

    k1<<<128, 1024, 0, stream>>>(x, Wp1);
    k2<<<152, 1024, 0, stream>>>(se, Wf1, bp1, Wp2, Wsel1, out_bw);
    k3<<<260,  512, 0, stream>>>(bf1, Wf2, bf2v, bp2, bsel1, Wsel2, bsel2,
                                 x, nw, out_fit, out_selw, out_best, out_x);
}